// Round 10
// baseline (231.071 us; speedup 1.0000x reference)
//
#include <hip/hip_runtime.h>

#define NN 50000
#define NE 800000
#define NG 512
#define CAP 64   // fixed bucket capacity; in-degree ~ Poisson(16), P(>64) ~ 1e-20
#define NP 196   // partitions of 256 nodes: ceil(50000/256)
#define CH 3200  // edges per chunk (= 800 int4)
#define NCH 250  // 800000 / 3200 exactly

// ---------- p1: per-chunk coarse histogram (dst>>8) + partition totals ----------
__global__ __launch_bounds__(256) void p1_hist_k(const int4* __restrict__ dst4,
                                                 int* __restrict__ Ht,
                                                 int* __restrict__ tot) {
    __shared__ int lh[NP];
    int t = threadIdx.x, b = blockIdx.x;
    if (t < NP) lh[t] = 0;
    __syncthreads();
    int i0 = b * (CH / 4);
    for (int i = i0 + t; i < i0 + CH / 4; i += 256) {
        int4 d = dst4[i];
        atomicAdd(&lh[d.x >> 8], 1);
        atomicAdd(&lh[d.y >> 8], 1);
        atomicAdd(&lh[d.z >> 8], 1);
        atomicAdd(&lh[d.w >> 8], 1);
    }
    __syncthreads();
    if (t < NP) {
        Ht[t * NCH + b] = lh[t];
        atomicAdd(&tot[t], lh[t]);
    }
}

// ---------- p2: per-partition — start[p] from tot prefix + row scan (start folded) ----------
__global__ __launch_bounds__(256) void p2_k(int* __restrict__ Ht,
                                            const int* __restrict__ tot,
                                            int* __restrict__ start) {
    __shared__ int sh[256];
    int p = blockIdx.x, t = threadIdx.x;
    sh[t] = (t < p) ? tot[t] : 0;  // NP=196 < 256
    __syncthreads();
    for (int off = 128; off > 0; off >>= 1) {
        if (t < off) sh[t] += sh[t + off];
        __syncthreads();
    }
    int start_p = sh[0];
    __syncthreads();
    if (t == 0) start[p] = start_p;
    if (p == 0 && t == 1) start[NP] = NE;
    int v = (t < NCH) ? Ht[p * NCH + t] : 0;
    sh[t] = v;
    __syncthreads();
    for (int off = 1; off < 256; off <<= 1) {
        int x = (t >= off) ? sh[t - off] : 0;
        __syncthreads();
        sh[t] += x;
        __syncthreads();
    }
    if (t < NCH) Ht[p * NCH + t] = start_p + sh[t] - v;
}

// ---------- p3: place packed (dl<<16 | src) into partition segments ----------
__global__ __launch_bounds__(256) void p3_place_k(const int4* __restrict__ src4,
                                                  const int4* __restrict__ dst4,
                                                  const int* __restrict__ Ht,
                                                  int* __restrict__ pak) {
    __shared__ int cur[NP];
    int t = threadIdx.x, b = blockIdx.x;
    if (t < NP) cur[t] = Ht[t * NCH + b];  // start already folded in
    __syncthreads();
    int i0 = b * (CH / 4);
    for (int i = i0 + t; i < i0 + CH / 4; i += 256) {
        int4 d = dst4[i];
        int4 s = src4[i];
        int pos;
        pos = atomicAdd(&cur[d.x >> 8], 1); pak[pos] = s.x | ((d.x & 255) << 16);
        pos = atomicAdd(&cur[d.y >> 8], 1); pak[pos] = s.y | ((d.y & 255) << 16);
        pos = atomicAdd(&cur[d.z >> 8], 1); pak[pos] = s.z | ((d.z & 255) << 16);
        pos = atomicAdd(&cur[d.w >> 8], 1); pak[pos] = s.w | ((d.w & 255) << 16);
    }
}

// ---------- p4: per-partition fine bucket build + deg/dinv/xs + degree-bin hist ----------
__global__ __launch_bounds__(256) void p4_build_k(const int* __restrict__ pak,
                                                   const int* __restrict__ start,
                                                   const float* __restrict__ x,
                                                   int* __restrict__ fill,
                                                   float* __restrict__ dinv,
                                                   float* __restrict__ xs,
                                                   int* __restrict__ eidx,
                                                   int* __restrict__ bins, int n) {
    __shared__ int lh[256], curn[256], binh[64];
    int p = blockIdx.x, t = threadIdx.x;
    lh[t] = 0;
    curn[t] = 0;
    if (t < 64) binh[t] = 0;
    __syncthreads();
    int s0 = start[p], s1 = start[p + 1];
    for (int i = s0 + t; i < s1; i += 256) atomicAdd(&lh[pak[i] >> 16], 1);
    __syncthreads();
    int node = p * 256 + t;
    if (node < n) {
        int dg = lh[t];
        fill[node] = dg;
        atomicAdd(&binh[min(dg, 63)], 1);  // LDS degree histogram
        float d = rsqrtf((float)(dg + 1));  // +1 self-loop
        dinv[node] = d;
        float4 v;
        v.x = x[node * 3 + 0] * d;
        v.y = x[node * 3 + 1] * d;
        v.z = x[node * 3 + 2] * d;
        v.w = 0.0f;
        *(float4*)(xs + (size_t)node * 4) = v;
    }
    __syncthreads();
    if (t < 64 && binh[t] > 0) atomicAdd(&bins[t], binh[t]);
    for (int i = s0 + t; i < s1; i += 256) {
        int w = pak[i];
        int dl = w >> 16, s = w & 0xFFFF;
        int pos = atomicAdd(&curn[dl], 1) & (CAP - 1);
        eidx[(size_t)(p * 256 + dl) * CAP + pos] = s;
    }
}

// ---------- p5: exclusive scan of 64 degree bins ----------
__global__ __launch_bounds__(64) void p5_binscan_k(const int* __restrict__ bins,
                                                   int* __restrict__ binstart) {
    __shared__ int sh[64];
    int t = threadIdx.x;
    int v = bins[t];
    sh[t] = v;
    __syncthreads();
    for (int off = 1; off < 64; off <<= 1) {
        int x = (t >= off) ? sh[t - off] : 0;
        __syncthreads();
        sh[t] += x;
        __syncthreads();
    }
    binstart[t] = sh[t] - v;
}

// ---------- p6: place nodes into degree-sorted perm (block-privatized) ----------
__global__ __launch_bounds__(256) void p6_binplace_k(const int* __restrict__ fill,
                                                     const int* __restrict__ binstart,
                                                     int* __restrict__ bincur,
                                                     int* __restrict__ perm,
                                                     int* __restrict__ degp, int n) {
    __shared__ int binh[64], base[64], cur2[64];
    int t = threadIdx.x;
    int node = blockIdx.x * 256 + t;
    if (t < 64) { binh[t] = 0; cur2[t] = 0; }
    __syncthreads();
    int dg = 0;
    if (node < n) {
        dg = min(fill[node], 63);
        atomicAdd(&binh[dg], 1);
    }
    __syncthreads();
    if (t < 64 && binh[t] > 0) base[t] = atomicAdd(&bincur[t], binh[t]);
    __syncthreads();
    if (node < n) {
        int r = atomicAdd(&cur2[dg], 1);
        int pos = binstart[dg] + base[dg] + r;
        perm[pos] = node;
        degp[pos] = dg;
    }
}

// ---------- fused layer 1: gather xs (4-wide) + matmul 3->32, degree-sorted ----------
__global__ __launch_bounds__(256) void fused_l1_k(
    const int* __restrict__ degp, const int* __restrict__ perm,
    const int* __restrict__ eidx,
    const float* __restrict__ xs, const float* __restrict__ W1,
    const float* __restrict__ b1, const float* __restrict__ dinv,
    float* __restrict__ A2, int n) {
    __shared__ float act[64][4];
    __shared__ int nd[64];
    int t = threadIdx.x;
    int i0 = blockIdx.x * 64;
    {   // gather phase: 4 lanes per node
        int i = i0 + (t >> 2);
        int f = t & 3;
        if (i < n) {
            int node = perm[i];
            if (f == 0) nd[t >> 2] = node;
            int e1 = degp[i];
            const int* __restrict__ eb = eidx + node * CAP;
            float acc = xs[(size_t)node * 4 + f];  // self-loop
            int e = 0;
            for (; e + 4 <= e1; e += 4) {
                int4 s = *(const int4*)(eb + e);
                float v0 = xs[(size_t)s.x * 4 + f];
                float v1 = xs[(size_t)s.y * 4 + f];
                float v2 = xs[(size_t)s.z * 4 + f];
                float v3 = xs[(size_t)s.w * 4 + f];
                acc += (v0 + v1) + (v2 + v3);
            }
            for (; e < e1; ++e) acc += xs[(size_t)eb[e] * 4 + f];
            act[t >> 2][f] = acc;
        }
    }
    __syncthreads();
    int f = t & 31;
    int nl0 = t >> 5;  // 0..7
#pragma unroll
    for (int q = 0; q < 8; ++q) {
        int nl = nl0 + q * 8;
        int i = i0 + nl;
        if (i < n) {
            int node = nd[nl];
            float acc = act[nl][0] * W1[f] + act[nl][1] * W1[32 + f] + act[nl][2] * W1[64 + f];
            float s = dinv[node];
            A2[(size_t)node * 32 + f] = fmaxf(fmaf(s, acc, b1[f]), 0.0f) * s;
        }
    }
}

// ---------- degree-sorted vectorized gather: unroll-16, 4 accumulators ----------
template <int F>
__global__ __launch_bounds__(256) void gather4_k(const int* __restrict__ degp,
                                                 const int* __restrict__ perm,
                                                 const int* __restrict__ eidx,
                                                 const float* __restrict__ A,
                                                 float* __restrict__ B, int n) {
    constexpr int FV = F / 4;
    constexpr int NPB = 256 / FV;
    int t = threadIdx.x;
    int i = blockIdx.x * NPB + t / FV;
    int j = (t % FV) * 4;
    if (i >= n) return;
    int node = perm[i];
    int e1 = degp[i];
    const int* __restrict__ eb = eidx + node * CAP;
    const float* __restrict__ Aj = A + j;
    float4 a0 = *(const float4*)(Aj + (size_t)node * F);  // self-loop
    float4 a1 = make_float4(0.f, 0.f, 0.f, 0.f);
    float4 a2 = make_float4(0.f, 0.f, 0.f, 0.f);
    float4 a3 = make_float4(0.f, 0.f, 0.f, 0.f);
    int e = 0;
    for (; e + 16 <= e1; e += 16) {  // 16 outstanding row-loads per lane
        int4 sa = *(const int4*)(eb + e);
        int4 sb = *(const int4*)(eb + e + 4);
        int4 sc = *(const int4*)(eb + e + 8);
        int4 sd = *(const int4*)(eb + e + 12);
        float4 v0 = *(const float4*)(Aj + (size_t)sa.x * F);
        float4 v1 = *(const float4*)(Aj + (size_t)sa.y * F);
        float4 v2 = *(const float4*)(Aj + (size_t)sa.z * F);
        float4 v3 = *(const float4*)(Aj + (size_t)sa.w * F);
        float4 v4 = *(const float4*)(Aj + (size_t)sb.x * F);
        float4 v5 = *(const float4*)(Aj + (size_t)sb.y * F);
        float4 v6 = *(const float4*)(Aj + (size_t)sb.z * F);
        float4 v7 = *(const float4*)(Aj + (size_t)sb.w * F);
        float4 v8 = *(const float4*)(Aj + (size_t)sc.x * F);
        float4 v9 = *(const float4*)(Aj + (size_t)sc.y * F);
        float4 va = *(const float4*)(Aj + (size_t)sc.z * F);
        float4 vb = *(const float4*)(Aj + (size_t)sc.w * F);
        float4 vc = *(const float4*)(Aj + (size_t)sd.x * F);
        float4 vd = *(const float4*)(Aj + (size_t)sd.y * F);
        float4 ve = *(const float4*)(Aj + (size_t)sd.z * F);
        float4 vf = *(const float4*)(Aj + (size_t)sd.w * F);
        a0.x += (v0.x + v1.x) + (v2.x + v3.x);
        a0.y += (v0.y + v1.y) + (v2.y + v3.y);
        a0.z += (v0.z + v1.z) + (v2.z + v3.z);
        a0.w += (v0.w + v1.w) + (v2.w + v3.w);
        a1.x += (v4.x + v5.x) + (v6.x + v7.x);
        a1.y += (v4.y + v5.y) + (v6.y + v7.y);
        a1.z += (v4.z + v5.z) + (v6.z + v7.z);
        a1.w += (v4.w + v5.w) + (v6.w + v7.w);
        a2.x += (v8.x + v9.x) + (va.x + vb.x);
        a2.y += (v8.y + v9.y) + (va.y + vb.y);
        a2.z += (v8.z + v9.z) + (va.z + vb.z);
        a2.w += (v8.w + v9.w) + (va.w + vb.w);
        a3.x += (vc.x + vd.x) + (ve.x + vf.x);
        a3.y += (vc.y + vd.y) + (ve.y + vf.y);
        a3.z += (vc.z + vd.z) + (ve.z + vf.z);
        a3.w += (vc.w + vd.w) + (ve.w + vf.w);
    }
    for (; e + 4 <= e1; e += 4) {
        int4 sa = *(const int4*)(eb + e);
        float4 v0 = *(const float4*)(Aj + (size_t)sa.x * F);
        float4 v1 = *(const float4*)(Aj + (size_t)sa.y * F);
        float4 v2 = *(const float4*)(Aj + (size_t)sa.z * F);
        float4 v3 = *(const float4*)(Aj + (size_t)sa.w * F);
        a1.x += (v0.x + v1.x) + (v2.x + v3.x);
        a1.y += (v0.y + v1.y) + (v2.y + v3.y);
        a1.z += (v0.z + v1.z) + (v2.z + v3.z);
        a1.w += (v0.w + v1.w) + (v2.w + v3.w);
    }
    for (; e < e1; ++e) {
        float4 v = *(const float4*)(Aj + (size_t)eb[e] * F);
        a0.x += v.x; a0.y += v.y; a0.z += v.z; a0.w += v.w;
    }
    a0.x += (a1.x + a2.x) + a3.x;
    a0.y += (a1.y + a2.y) + a3.y;
    a0.z += (a1.z + a2.z) + a3.z;
    a0.w += (a1.w + a2.w) + a3.w;
    *(float4*)(B + (size_t)node * F + j) = a0;
}

// ---------- register-tiled matmul: NPT nodes x 4 f per thread ----------
template <int Fin, int Fout, int NPB, bool SCALE_OUT>
__global__ __launch_bounds__(256) void mmB_k(
    const float* __restrict__ G, const float* __restrict__ W,
    const float* __restrict__ bias, const float* __restrict__ dinv,
    float* __restrict__ Aout, int n) {
    constexpr int FL = Fout / 4;        // f-lanes
    constexpr int NGRP = 256 / FL;      // node groups per block
    constexpr int NPT = NPB / NGRP;     // nodes per thread
    __shared__ float act[NPB][Fin];
    int t = threadIdx.x;
    int node0 = blockIdx.x * NPB;
    constexpr int TOT4 = NPB * Fin / 4;
    const float4* __restrict__ G4 = (const float4*)(G + (size_t)node0 * Fin);
    float4* act4 = (float4*)&act[0][0];
    for (int i = t; i < TOT4; i += 256) {
        int nl = i / (Fin / 4);
        float4 v = make_float4(0.f, 0.f, 0.f, 0.f);
        if (node0 + nl < n) v = G4[i];
        act4[i] = v;
    }
    __syncthreads();
    int f4 = (t % FL) * 4;
    int nlbase = (t / FL) * NPT;
    float4 acc[NPT];
#pragma unroll
    for (int i = 0; i < NPT; ++i) acc[i] = make_float4(0.f, 0.f, 0.f, 0.f);
    for (int k = 0; k < Fin; k += 4) {
        float4 a[NPT];
#pragma unroll
        for (int i = 0; i < NPT; ++i) a[i] = *(const float4*)&act[nlbase + i][k];
#pragma unroll
        for (int kk = 0; kk < 4; ++kk) {
            float4 w = *(const float4*)(W + (size_t)(k + kk) * Fout + f4);
#pragma unroll
            for (int i = 0; i < NPT; ++i) {
                float av = (&a[i].x)[kk];
                acc[i].x = fmaf(av, w.x, acc[i].x);
                acc[i].y = fmaf(av, w.y, acc[i].y);
                acc[i].z = fmaf(av, w.z, acc[i].z);
                acc[i].w = fmaf(av, w.w, acc[i].w);
            }
        }
    }
    float4 bv = *(const float4*)(bias + f4);
#pragma unroll
    for (int i = 0; i < NPT; ++i) {
        int node = node0 + nlbase + i;
        if (node < n) {
            float s = dinv[node];
            float4 o;
            o.x = fmaxf(fmaf(s, acc[i].x, bv.x), 0.0f);
            o.y = fmaxf(fmaf(s, acc[i].y, bv.y), 0.0f);
            o.z = fmaxf(fmaf(s, acc[i].z, bv.z), 0.0f);
            o.w = fmaxf(fmaf(s, acc[i].w, bv.w), 0.0f);
            if (SCALE_OUT) { o.x *= s; o.y *= s; o.z *= s; o.w *= s; }
            *(float4*)(Aout + (size_t)node * Fout + f4) = o;
        }
    }
}

// ---------- fused mean-pool + MLP head: one block per graph, 2 row-teams ----------
__device__ __forceinline__ int lbound_d(const int* __restrict__ a, int n, int key) {
    int lo = 0, hi = n;
    while (lo < hi) {
        int m = (lo + hi) >> 1;
        if (a[m] < key) lo = m + 1; else hi = m;
    }
    return lo;
}

__global__ __launch_bounds__(256) void poolhead_k(
    const float* __restrict__ H, const int* __restrict__ batch,
    const float* __restrict__ Wf1, const float* __restrict__ bf1,
    const float* __restrict__ Wf2, const float* __restrict__ bf2,
    float* __restrict__ out, int n) {
    __shared__ int bnd[2];
    __shared__ float pm2[2][128];
    __shared__ float z[32];
    int g = blockIdx.x, t = threadIdx.x;
    if (t == 0) bnd[0] = lbound_d(batch, n, g);
    if (t == 1) bnd[1] = lbound_d(batch, n, g + 1);
    __syncthreads();
    int lo = bnd[0], hi = bnd[1];
    int f = t & 127, r = t >> 7;  // team r handles rows lo+r, lo+r+2, ...
    float s0 = 0.f, s1 = 0.f;
    int i = lo + r;
    for (; i + 2 < hi; i += 4) {
        s0 += H[(size_t)i * 128 + f];
        s1 += H[(size_t)(i + 2) * 128 + f];
    }
    if (i < hi) s0 += H[(size_t)i * 128 + f];
    pm2[r][f] = s0 + s1;
    __syncthreads();
    if (t < 128) {
        float c = fmaxf((float)(hi - lo), 1.0f);
        pm2[0][t] = (pm2[0][t] + pm2[1][t]) / c;
    }
    __syncthreads();
    if (t < 32) {
        float acc = bf1[t];
#pragma unroll 4
        for (int k = 0; k < 128; ++k) acc = fmaf(pm2[0][k], Wf1[k * 32 + t], acc);
        z[t] = fmaxf(acc, 0.0f);
    }
    __syncthreads();
    if (t < 4) {
        float acc = bf2[t];
#pragma unroll
        for (int jj = 0; jj < 32; ++jj) acc = fmaf(z[jj], Wf2[jj * 4 + t], acc);
        out[g * 4 + t] = acc;
    }
}

extern "C" void kernel_launch(void* const* d_in, const int* in_sizes, int n_in,
                              void* d_out, int out_size, void* d_ws, size_t ws_size,
                              hipStream_t stream) {
    const float* x    = (const float*)d_in[0];
    const int*   ei   = (const int*)d_in[1];
    const int*   batch= (const int*)d_in[2];
    const float* W1   = (const float*)d_in[3];
    const float* b1   = (const float*)d_in[4];
    const float* W2   = (const float*)d_in[5];
    const float* b2   = (const float*)d_in[6];
    const float* W3   = (const float*)d_in[7];
    const float* b3   = (const float*)d_in[8];
    const float* Wf1  = (const float*)d_in[9];
    const float* bf1  = (const float*)d_in[10];
    const float* Wf2  = (const float*)d_in[11];
    const float* bf2  = (const float*)d_in[12];
    float* out = (float*)d_out;

    // workspace layout (4-byte elems)
    int*   fill   = (int*)d_ws;                     // N (in-degree)
    float* dinv   = (float*)(fill + NN);            // N
    float* xs     = dinv + NN;                      // N*4
    float* A2     = xs + (size_t)NN * 4;            // N*32
    float* A3     = A2 + (size_t)NN * 32;           // N*64
    float* H3     = A3 + (size_t)NN * 64;           // N*128
    float* G      = H3 + (size_t)NN * 128;          // N*64 (gather scratch)
    int*   perm   = (int*)(G + (size_t)NN * 64);    // N (degree-sorted node order)
    int*   degp   = perm + NN;                      // N (degree in perm order)
    int*   eidx   = degp + NN;                      // N*CAP

    // builder scratch aliased onto later-used buffers (no ws growth):
    int* pak   = (int*)G;    // NE ints (G used only from gather<32> onwards)
    int* Ht    = (int*)H3;   // NP*NCH ints (H3 written only by last mmB)
    int* tot      = Ht + NP * NCH;   // NP   } zeroed in one memset
    int* bins     = tot + NP;        // 64   }
    int* bincur   = bins + 64;       // 64   }
    int* start    = bincur + 64;     // NP+1
    int* binstart = start + NP + 1;  // 64

    const int4* src4 = (const int4*)ei;
    const int4* dst4 = (const int4*)(ei + NE);

    // ---- deterministic two-level counting sort + degree-sorted perm ----
    hipMemsetAsync(tot, 0, (NP + 128) * 4, stream);
    p1_hist_k<<<NCH, 256, 0, stream>>>(dst4, Ht, tot);
    p2_k<<<NP, 256, 0, stream>>>(Ht, tot, start);
    p3_place_k<<<NCH, 256, 0, stream>>>(src4, dst4, Ht, pak);
    p4_build_k<<<NP, 256, 0, stream>>>(pak, start, x, fill, dinv, xs, eidx, bins, NN);
    p5_binscan_k<<<1, 64, 0, stream>>>(bins, binstart);
    p6_binplace_k<<<NP, 256, 0, stream>>>(fill, binstart, bincur, perm, degp, NN);

    // ---- layer 1 (fused: tiny), degree-sorted order ----
    fused_l1_k<<<(NN + 63) / 64, 256, 0, stream>>>(degp, perm, eidx, xs, W1, b1, dinv, A2, NN);

    // ---- layer 2: gather 32-wide (degree-sorted), then register-tiled matmul ----
    gather4_k<32><<<(NN + 31) / 32, 256, 0, stream>>>(degp, perm, eidx, A2, G, NN);
    mmB_k<32, 64, 32, true><<<(NN + 31) / 32, 256, 0, stream>>>(G, W2, b2, dinv, A3, NN);

    // ---- layer 3: gather 64-wide (degree-sorted), then register-tiled matmul ----
    gather4_k<64><<<(NN + 15) / 16, 256, 0, stream>>>(degp, perm, eidx, A3, G, NN);
    mmB_k<64, 128, 32, false><<<(NN + 31) / 32, 256, 0, stream>>>(G, W3, b3, dinv, H3, NN);

    // ---- fused mean-pool + head ----
    poolhead_k<<<NG, 256, 0, stream>>>(H3, batch, Wf1, bf1, Wf2, bf2, out, NN);
}

// Round 11
// 222.236 us; speedup vs baseline: 1.0398x; 1.0398x over previous
//
#include <hip/hip_runtime.h>

#define NN 50000
#define NE 800000
#define NG 512
#define CAP 64   // fixed bucket capacity; in-degree ~ Poisson(16), P(>64) ~ 1e-20
#define NP 196   // partitions of 256 nodes: ceil(50000/256)
#define CH 3200  // edges per chunk
#define NCH 250  // ceil(800000/3200)

// ---------- p1: per-chunk coarse histogram (dst>>8), transposed store ----------
__global__ __launch_bounds__(256) void p1_hist_k(const int* __restrict__ dst,
                                                 int* __restrict__ Ht, int e) {
    __shared__ int lh[NP];
    int t = threadIdx.x, b = blockIdx.x;
    if (t < NP) lh[t] = 0;
    __syncthreads();
    int i0 = b * CH, i1 = min(e, i0 + CH);
    for (int i = i0 + t; i < i1; i += 256) atomicAdd(&lh[dst[i] >> 8], 1);
    __syncthreads();
    if (t < NP) Ht[t * NCH + b] = lh[t];
}

// ---------- p2a: exclusive scan each partition's chunk-counts row ----------
__global__ __launch_bounds__(256) void p2a_k(int* __restrict__ Ht, int* __restrict__ tot) {
    __shared__ int sh[256];
    int p = blockIdx.x, t = threadIdx.x;
    int v = (t < NCH) ? Ht[p * NCH + t] : 0;
    sh[t] = v;
    __syncthreads();
    for (int off = 1; off < 256; off <<= 1) {
        int x = (t >= off) ? sh[t - off] : 0;
        __syncthreads();
        sh[t] += x;
        __syncthreads();
    }
    if (t < NCH) Ht[p * NCH + t] = sh[t] - v;
    if (t == 255) tot[p] = sh[255];
}

// ---------- p2b: exclusive scan partition totals -> start[NP+1] ----------
__global__ __launch_bounds__(256) void p2b_k(const int* __restrict__ tot,
                                             int* __restrict__ start) {
    __shared__ int sh[256];
    int t = threadIdx.x;
    int v = (t < NP) ? tot[t] : 0;
    sh[t] = v;
    __syncthreads();
    for (int off = 1; off < 256; off <<= 1) {
        int x = (t >= off) ? sh[t - off] : 0;
        __syncthreads();
        sh[t] += x;
        __syncthreads();
    }
    if (t < NP) start[t] = sh[t] - v;
    if (t == 255) start[NP] = sh[255];
}

// ---------- p3: place packed (dl<<16 | src) into partition segments ----------
__global__ __launch_bounds__(256) void p3_place_k(const int* __restrict__ src,
                                                  const int* __restrict__ dst,
                                                  const int* __restrict__ Ht,
                                                  const int* __restrict__ start,
                                                  int* __restrict__ pak, int e) {
    __shared__ int cur[NP];
    int t = threadIdx.x, b = blockIdx.x;
    if (t < NP) cur[t] = start[t] + Ht[t * NCH + b];
    __syncthreads();
    int i0 = b * CH, i1 = min(e, i0 + CH);
    for (int i = i0 + t; i < i1; i += 256) {
        int d = dst[i], s = src[i];
        int p = d >> 8, dl = d & 255;
        int pos = atomicAdd(&cur[p], 1);  // LDS atomic — fast
        pak[pos] = s | (dl << 16);
    }
}

// ---------- p4: per-partition fine bucket build + deg/dinv/xs (fused) ----------
__global__ __launch_bounds__(256) void p4_build_k(const int* __restrict__ pak,
                                                   const int* __restrict__ start,
                                                   const float* __restrict__ x,
                                                   int* __restrict__ fill,
                                                   float* __restrict__ dinv,
                                                   float* __restrict__ xs,
                                                   int* __restrict__ eidx, int n) {
    __shared__ int lh[256], curn[256];
    int p = blockIdx.x, t = threadIdx.x;
    lh[t] = 0;
    curn[t] = 0;
    __syncthreads();
    int s0 = start[p], s1 = start[p + 1];
    for (int i = s0 + t; i < s1; i += 256) atomicAdd(&lh[pak[i] >> 16], 1);
    __syncthreads();
    int node = p * 256 + t;
    if (node < n) {
        int dg = lh[t];
        fill[node] = dg;
        float d = rsqrtf((float)(dg + 1));  // +1 self-loop
        dinv[node] = d;
        float4 v;
        v.x = x[node * 3 + 0] * d;
        v.y = x[node * 3 + 1] * d;
        v.z = x[node * 3 + 2] * d;
        v.w = 0.0f;
        *(float4*)(xs + (size_t)node * 4) = v;
    }
    __syncthreads();
    for (int i = s0 + t; i < s1; i += 256) {
        int w = pak[i];
        int dl = w >> 16, s = w & 0xFFFF;
        int pos = atomicAdd(&curn[dl], 1) & (CAP - 1);
        eidx[(size_t)(p * 256 + dl) * CAP + pos] = s;
    }
}

// ---------- fused layer 1: gather xs (4-wide) + matmul 3->32 ----------
__global__ __launch_bounds__(256) void fused_l1_k(
    const int* __restrict__ deg, const int* __restrict__ eidx,
    const float* __restrict__ xs, const float* __restrict__ W1,
    const float* __restrict__ b1, const float* __restrict__ dinv,
    float* __restrict__ A2, int n) {
    __shared__ float act[64][4];
    int t = threadIdx.x;
    int node0 = blockIdx.x * 64;
    {   // gather phase: 4 lanes per node
        int node = node0 + (t >> 2);
        int f = t & 3;
        if (node < n) {
            int e1 = deg[node];
            const int* __restrict__ eb = eidx + node * CAP;
            float acc = xs[(size_t)node * 4 + f];  // self-loop
            int e = 0;
            for (; e + 4 <= e1; e += 4) {
                int4 s = *(const int4*)(eb + e);
                float v0 = xs[(size_t)s.x * 4 + f];
                float v1 = xs[(size_t)s.y * 4 + f];
                float v2 = xs[(size_t)s.z * 4 + f];
                float v3 = xs[(size_t)s.w * 4 + f];
                acc += (v0 + v1) + (v2 + v3);
            }
            for (; e < e1; ++e) acc += xs[(size_t)eb[e] * 4 + f];
            act[t >> 2][f] = acc;
        }
    }
    __syncthreads();
    int f = t & 31;
    int nl0 = t >> 5;  // 0..7
#pragma unroll
    for (int i = 0; i < 8; ++i) {
        int nl = nl0 + i * 8;
        int node = node0 + nl;
        if (node < n) {
            float acc = act[nl][0] * W1[f] + act[nl][1] * W1[32 + f] + act[nl][2] * W1[64 + f];
            float s = dinv[node];
            A2[(size_t)node * 32 + f] = fmaxf(fmaf(s, acc, b1[f]), 0.0f) * s;
        }
    }
}

// ---------- standalone vectorized gather: unroll-16, 4 accumulators ----------
// B[d,:] = A[d,:] + sum_{s in bucket[d]} A[s,:]
template <int F>
__global__ __launch_bounds__(256) void gather4_k(const int* __restrict__ deg,
                                                 const int* __restrict__ eidx,
                                                 const float* __restrict__ A,
                                                 float* __restrict__ B, int n) {
    constexpr int FV = F / 4;
    constexpr int NPB = 256 / FV;
    int t = threadIdx.x;
    int node = blockIdx.x * NPB + t / FV;
    int j = (t % FV) * 4;
    if (node >= n) return;
    int e1 = deg[node];
    const int* __restrict__ eb = eidx + node * CAP;
    const float* __restrict__ Aj = A + j;
    float4 a0 = *(const float4*)(Aj + (size_t)node * F);  // self-loop
    float4 a1 = make_float4(0.f, 0.f, 0.f, 0.f);
    float4 a2 = make_float4(0.f, 0.f, 0.f, 0.f);
    float4 a3 = make_float4(0.f, 0.f, 0.f, 0.f);
    int e = 0;
    for (; e + 16 <= e1; e += 16) {  // 16 outstanding row-loads per lane
        int4 sa = *(const int4*)(eb + e);
        int4 sb = *(const int4*)(eb + e + 4);
        int4 sc = *(const int4*)(eb + e + 8);
        int4 sd = *(const int4*)(eb + e + 12);
        float4 v0 = *(const float4*)(Aj + (size_t)sa.x * F);
        float4 v1 = *(const float4*)(Aj + (size_t)sa.y * F);
        float4 v2 = *(const float4*)(Aj + (size_t)sa.z * F);
        float4 v3 = *(const float4*)(Aj + (size_t)sa.w * F);
        float4 v4 = *(const float4*)(Aj + (size_t)sb.x * F);
        float4 v5 = *(const float4*)(Aj + (size_t)sb.y * F);
        float4 v6 = *(const float4*)(Aj + (size_t)sb.z * F);
        float4 v7 = *(const float4*)(Aj + (size_t)sb.w * F);
        float4 v8 = *(const float4*)(Aj + (size_t)sc.x * F);
        float4 v9 = *(const float4*)(Aj + (size_t)sc.y * F);
        float4 va = *(const float4*)(Aj + (size_t)sc.z * F);
        float4 vb = *(const float4*)(Aj + (size_t)sc.w * F);
        float4 vc = *(const float4*)(Aj + (size_t)sd.x * F);
        float4 vd = *(const float4*)(Aj + (size_t)sd.y * F);
        float4 ve = *(const float4*)(Aj + (size_t)sd.z * F);
        float4 vf = *(const float4*)(Aj + (size_t)sd.w * F);
        a0.x += (v0.x + v1.x) + (v2.x + v3.x);
        a0.y += (v0.y + v1.y) + (v2.y + v3.y);
        a0.z += (v0.z + v1.z) + (v2.z + v3.z);
        a0.w += (v0.w + v1.w) + (v2.w + v3.w);
        a1.x += (v4.x + v5.x) + (v6.x + v7.x);
        a1.y += (v4.y + v5.y) + (v6.y + v7.y);
        a1.z += (v4.z + v5.z) + (v6.z + v7.z);
        a1.w += (v4.w + v5.w) + (v6.w + v7.w);
        a2.x += (v8.x + v9.x) + (va.x + vb.x);
        a2.y += (v8.y + v9.y) + (va.y + vb.y);
        a2.z += (v8.z + v9.z) + (va.z + vb.z);
        a2.w += (v8.w + v9.w) + (va.w + vb.w);
        a3.x += (vc.x + vd.x) + (ve.x + vf.x);
        a3.y += (vc.y + vd.y) + (ve.y + vf.y);
        a3.z += (vc.z + vd.z) + (ve.z + vf.z);
        a3.w += (vc.w + vd.w) + (ve.w + vf.w);
    }
    for (; e + 4 <= e1; e += 4) {
        int4 sa = *(const int4*)(eb + e);
        float4 v0 = *(const float4*)(Aj + (size_t)sa.x * F);
        float4 v1 = *(const float4*)(Aj + (size_t)sa.y * F);
        float4 v2 = *(const float4*)(Aj + (size_t)sa.z * F);
        float4 v3 = *(const float4*)(Aj + (size_t)sa.w * F);
        a1.x += (v0.x + v1.x) + (v2.x + v3.x);
        a1.y += (v0.y + v1.y) + (v2.y + v3.y);
        a1.z += (v0.z + v1.z) + (v2.z + v3.z);
        a1.w += (v0.w + v1.w) + (v2.w + v3.w);
    }
    for (; e < e1; ++e) {
        float4 v = *(const float4*)(Aj + (size_t)eb[e] * F);
        a0.x += v.x; a0.y += v.y; a0.z += v.z; a0.w += v.w;
    }
    a0.x += (a1.x + a2.x) + a3.x;
    a0.y += (a1.y + a2.y) + a3.y;
    a0.z += (a1.z + a2.z) + a3.z;
    a0.w += (a1.w + a2.w) + a3.w;
    *(float4*)(B + (size_t)node * F + j) = a0;
}

// ---------- register-tiled matmul: NPT nodes x 4 f per thread ----------
template <int Fin, int Fout, int NPB, bool SCALE_OUT>
__global__ __launch_bounds__(256) void mmB_k(
    const float* __restrict__ G, const float* __restrict__ W,
    const float* __restrict__ bias, const float* __restrict__ dinv,
    float* __restrict__ Aout, int n) {
    constexpr int FL = Fout / 4;        // f-lanes
    constexpr int NGRP = 256 / FL;      // node groups per block
    constexpr int NPT = NPB / NGRP;     // nodes per thread
    __shared__ float act[NPB][Fin];
    int t = threadIdx.x;
    int node0 = blockIdx.x * NPB;
    constexpr int TOT4 = NPB * Fin / 4;
    const float4* __restrict__ G4 = (const float4*)(G + (size_t)node0 * Fin);
    float4* act4 = (float4*)&act[0][0];
    for (int i = t; i < TOT4; i += 256) {
        int nl = i / (Fin / 4);
        float4 v = make_float4(0.f, 0.f, 0.f, 0.f);
        if (node0 + nl < n) v = G4[i];
        act4[i] = v;
    }
    __syncthreads();
    int f4 = (t % FL) * 4;
    int nlbase = (t / FL) * NPT;
    float4 acc[NPT];
#pragma unroll
    for (int i = 0; i < NPT; ++i) acc[i] = make_float4(0.f, 0.f, 0.f, 0.f);
    for (int k = 0; k < Fin; k += 4) {
        float4 a[NPT];
#pragma unroll
        for (int i = 0; i < NPT; ++i) a[i] = *(const float4*)&act[nlbase + i][k];
#pragma unroll
        for (int kk = 0; kk < 4; ++kk) {
            float4 w = *(const float4*)(W + (size_t)(k + kk) * Fout + f4);
#pragma unroll
            for (int i = 0; i < NPT; ++i) {
                float av = (&a[i].x)[kk];
                acc[i].x = fmaf(av, w.x, acc[i].x);
                acc[i].y = fmaf(av, w.y, acc[i].y);
                acc[i].z = fmaf(av, w.z, acc[i].z);
                acc[i].w = fmaf(av, w.w, acc[i].w);
            }
        }
    }
    float4 bv = *(const float4*)(bias + f4);
#pragma unroll
    for (int i = 0; i < NPT; ++i) {
        int node = node0 + nlbase + i;
        if (node < n) {
            float s = dinv[node];
            float4 o;
            o.x = fmaxf(fmaf(s, acc[i].x, bv.x), 0.0f);
            o.y = fmaxf(fmaf(s, acc[i].y, bv.y), 0.0f);
            o.z = fmaxf(fmaf(s, acc[i].z, bv.z), 0.0f);
            o.w = fmaxf(fmaf(s, acc[i].w, bv.w), 0.0f);
            if (SCALE_OUT) { o.x *= s; o.y *= s; o.z *= s; o.w *= s; }
            *(float4*)(Aout + (size_t)node * Fout + f4) = o;
        }
    }
}

// ---------- fused mean-pool + MLP head: one block per graph (batch sorted) ----------
__device__ __forceinline__ int lbound_d(const int* __restrict__ a, int n, int key) {
    int lo = 0, hi = n;
    while (lo < hi) {
        int m = (lo + hi) >> 1;
        if (a[m] < key) lo = m + 1; else hi = m;
    }
    return lo;
}

__global__ __launch_bounds__(128) void poolhead_k(
    const float* __restrict__ H, const int* __restrict__ batch,
    const float* __restrict__ Wf1, const float* __restrict__ bf1,
    const float* __restrict__ Wf2, const float* __restrict__ bf2,
    float* __restrict__ out, int n) {
    __shared__ int bnd[2];
    __shared__ float pm[128];
    __shared__ float z[32];
    int g = blockIdx.x, t = threadIdx.x;
    if (t == 0) bnd[0] = lbound_d(batch, n, g);
    if (t == 1) bnd[1] = lbound_d(batch, n, g + 1);
    __syncthreads();
    int lo = bnd[0], hi = bnd[1];
    float s0 = 0.f, s1 = 0.f, s2 = 0.f, s3 = 0.f;
    int i = lo;
    for (; i + 4 <= hi; i += 4) {  // coalesced: 128 lanes span the row
        s0 += H[(size_t)i * 128 + t];
        s1 += H[(size_t)(i + 1) * 128 + t];
        s2 += H[(size_t)(i + 2) * 128 + t];
        s3 += H[(size_t)(i + 3) * 128 + t];
    }
    for (; i < hi; ++i) s0 += H[(size_t)i * 128 + t];
    float c = (float)(hi - lo);
    c = fmaxf(c, 1.0f);
    pm[t] = ((s0 + s1) + (s2 + s3)) / c;
    __syncthreads();
    if (t < 32) {
        float acc = bf1[t];
#pragma unroll 4
        for (int k = 0; k < 128; ++k) acc = fmaf(pm[k], Wf1[k * 32 + t], acc);
        z[t] = fmaxf(acc, 0.0f);
    }
    __syncthreads();
    if (t < 4) {
        float acc = bf2[t];
#pragma unroll
        for (int jj = 0; jj < 32; ++jj) acc = fmaf(z[jj], Wf2[jj * 4 + t], acc);
        out[g * 4 + t] = acc;
    }
}

extern "C" void kernel_launch(void* const* d_in, const int* in_sizes, int n_in,
                              void* d_out, int out_size, void* d_ws, size_t ws_size,
                              hipStream_t stream) {
    const float* x    = (const float*)d_in[0];
    const int*   ei   = (const int*)d_in[1];
    const int*   batch= (const int*)d_in[2];
    const float* W1   = (const float*)d_in[3];
    const float* b1   = (const float*)d_in[4];
    const float* W2   = (const float*)d_in[5];
    const float* b2   = (const float*)d_in[6];
    const float* W3   = (const float*)d_in[7];
    const float* b3   = (const float*)d_in[8];
    const float* Wf1  = (const float*)d_in[9];
    const float* bf1  = (const float*)d_in[10];
    const float* Wf2  = (const float*)d_in[11];
    const float* bf2  = (const float*)d_in[12];
    float* out = (float*)d_out;

    // workspace layout (4-byte elems); every byte read is written first (ws is poisoned)
    int*   fill   = (int*)d_ws;                     // N (in-degree)
    float* dinv   = (float*)(fill + NN);            // N
    float* xs     = dinv + NN;                      // N*4
    float* A2     = xs + (size_t)NN * 4;            // N*32
    float* A3     = A2 + (size_t)NN * 32;           // N*64
    float* H3     = A3 + (size_t)NN * 64;           // N*128
    float* G      = H3 + (size_t)NN * 128;          // N*64 (gather scratch)
    int*   eidx   = (int*)(G + (size_t)NN * 64);    // N*CAP

    // builder scratch aliased onto later-used buffers (no ws growth):
    int* pak   = (int*)G;    // NE ints (G used only from gather<32> onwards)
    int* Ht    = (int*)H3;   // NP*NCH ints (H3 written only by last mmB)
    int* tot   = Ht + NP * NCH;   // 256
    int* start = tot + 256;       // NP+1

    const int* src = ei;
    const int* dst = ei + NE;

    // ---- deterministic two-level counting sort (no global data atomics) ----
    p1_hist_k<<<NCH, 256, 0, stream>>>(dst, Ht, NE);
    p2a_k<<<NP, 256, 0, stream>>>(Ht, tot);
    p2b_k<<<1, 256, 0, stream>>>(tot, start);
    p3_place_k<<<NCH, 256, 0, stream>>>(src, dst, Ht, start, pak, NE);
    p4_build_k<<<NP, 256, 0, stream>>>(pak, start, x, fill, dinv, xs, eidx, NN);

    // ---- layer 1 (fused: tiny) ----
    fused_l1_k<<<(NN + 63) / 64, 256, 0, stream>>>(fill, eidx, xs, W1, b1, dinv, A2, NN);

    // ---- layer 2: gather 32-wide, then register-tiled matmul ----
    gather4_k<32><<<(NN + 31) / 32, 256, 0, stream>>>(fill, eidx, A2, G, NN);
    mmB_k<32, 64, 32, true><<<(NN + 31) / 32, 256, 0, stream>>>(G, W2, b2, dinv, A3, NN);

    // ---- layer 3: gather 64-wide, then register-tiled matmul ----
    gather4_k<64><<<(NN + 15) / 16, 256, 0, stream>>>(fill, eidx, A3, G, NN);
    mmB_k<64, 128, 32, false><<<(NN + 31) / 32, 256, 0, stream>>>(G, W3, b3, dinv, H3, NN);

    // ---- fused mean-pool + head ----
    poolhead_k<<<NG, 128, 0, stream>>>(H3, batch, Wf1, bf1, Wf2, bf2, out, NN);
}